// Round 19
// baseline (6469.267 us; speedup 1.0000x reference)
//
#include <hip/hip_runtime.h>
#include <math.h>

#define NB 16
#define NC 512
#define NH 38
#define NW 50
#define NHW 1900          // 38*50
#define NPOS 30400        // 16*1900
#define NANCH 17100       // 1900*9
#define PRE_N 6000
#define POST_N 300
#define KTOT 4608         // 512*9
#define NTILE 475         // 19*25 Winograd F(2x2,3x3) tiles (38=19*2, 50=25*2)
#define IMGH 608.0f
#define IMGW 800.0f

// ---------------------------------------------------------------------------
// Kernel 1a: Winograd filter transform U_f = G g G^T (f64; 0.5 factors are
// exact). U layout [f=xi*4+nu][ci][co] for coalesced GEMM A-staging.
// Grid 1024 x 256 threads; thread handles one (ci, co).
// ---------------------------------------------------------------------------
__global__ __launch_bounds__(256)
void wino_filter(const float* __restrict__ w, double* __restrict__ U)
{
    const int p  = blockIdx.x * 256 + threadIdx.x;   // 0..262143
    const int ci = p >> 9;
    const int co = p & 511;
    const float* g = w + (size_t)co * KTOT + ci * 9;

    double gg[3][3];
#pragma unroll
    for (int r = 0; r < 3; ++r)
#pragma unroll
        for (int c = 0; c < 3; ++c) gg[r][c] = (double)g[r * 3 + c];

    double T[4][3];
#pragma unroll
    for (int c = 0; c < 3; ++c) {
        T[0][c] = gg[0][c];
        T[1][c] = 0.5 * (gg[0][c] + gg[1][c] + gg[2][c]);
        T[2][c] = 0.5 * (gg[0][c] - gg[1][c] + gg[2][c]);
        T[3][c] = gg[2][c];
    }
#pragma unroll
    for (int xi = 0; xi < 4; ++xi) {
        const double t0 = T[xi][0], t1 = T[xi][1], t2 = T[xi][2];
        double u[4];
        u[0] = t0;
        u[1] = 0.5 * (t0 + t1 + t2);
        u[2] = 0.5 * (t0 - t1 + t2);
        u[3] = t2;
#pragma unroll
        for (int nu = 0; nu < 4; ++nu)
            U[(((size_t)(xi * 4 + nu) * 512 + ci) * 512) + co] = u[nu];
    }
}

// ---------------------------------------------------------------------------
// Kernel 1b: Winograd conv: for each freq f, GEMM over ci (K=512) of
// U_f[ci][co] x V_f[ci][tile]; V computed on the fly (4 signed input reads
// per element, B^T rows have 2 nonzeros); Y = A^T M A accumulated in regs
// across f (coefs in {0,+-1}, exact). Bias+ReLU+f32 store as before.
// Block: 64co x 32tiles, thread 4co x 2tiles. Grid (15, 8, 16), block 256.
// ---------------------------------------------------------------------------
__global__ __launch_bounds__(256, 2)
void conv_wino(const float* __restrict__ x, const double* __restrict__ U,
               const float* __restrict__ bias, float* __restrict__ out)
{
    const int b   = blockIdx.z;
    const int co0 = blockIdx.y * 64;
    const int t0  = blockIdx.x * 32;

    __shared__ __align__(16) double Al[16][66];   // [ci][co]
    __shared__ __align__(16) double Bl[16][34];   // [ci][tile]

    const int tid = threadIdx.x;
    const int ty  = tid >> 4;    // co group: 4 consecutive co
    const int tx  = tid & 15;    // tile group: 2 consecutive tiles

    // B^T row tables: value(xi) combines rows R1 (sign S1) and R2 (sign S2)
    const int    R1[4] = {0, 1, 1, 1};
    const double S1[4] = {1.0, 1.0, -1.0, 1.0};
    const int    R2[4] = {2, 2, 2, 3};
    const double S2[4] = {-1.0, 1.0, 1.0, -1.0};
    // A^T rows: CA0 = [1,1,1,0], CA1 = [0,1,-1,-1]
    const double CA0[4] = {1.0, 1.0, 1.0, 0.0};
    const double CA1[4] = {0.0, 1.0, -1.0, -1.0};

    double y[4][2][2][2];   // [m][n][i][j]
#pragma unroll
    for (int m = 0; m < 4; ++m)
#pragma unroll
        for (int n = 0; n < 2; ++n)
#pragma unroll
            for (int i = 0; i < 2; ++i)
#pragma unroll
                for (int j = 0; j < 2; ++j) y[m][n][i][j] = 0.0;

    const float* xb = x + (size_t)b * NC * NHW;

    // B staging geometry (2 elements per thread), tile part is loop-invariant
    int  br0[2], bc0[2];
    bool bok[2];
#pragma unroll
    for (int e = 0; e < 2; ++e) {
        const int idx  = tid + e * 256;
        const int tloc = idx & 31;
        const int tg   = t0 + tloc;
        const bool v   = tg < NTILE;
        const int tgc  = v ? tg : 0;
        const int tyt  = tgc / 25;
        const int txt  = tgc - tyt * 25;
        br0[e] = 2 * tyt - 1;
        bc0[e] = 2 * txt - 1;
        bok[e] = v;
    }

    for (int f = 0; f < 16; ++f) {
        const int xi = f >> 2, nu = f & 3;
        const double* Uf = U + (size_t)f * 512 * 512;

        // per-f patch offsets/signs for this thread's 2 staged elements
        int ra[2], rb[2], ca[2], cb[2];
#pragma unroll
        for (int e = 0; e < 2; ++e) {
            ra[e] = br0[e] + R1[xi];
            rb[e] = br0[e] + R2[xi];
            ca[e] = bc0[e] + R1[nu];
            cb[e] = bc0[e] + R2[nu];
        }
        const double sx1 = S1[xi], sx2 = S2[xi];
        const double sn1 = S1[nu], sn2 = S2[nu];

        double acc[4][2];
#pragma unroll
        for (int m = 0; m < 4; ++m)
#pragma unroll
            for (int n = 0; n < 2; ++n) acc[m][n] = 0.0;

        for (int ci0 = 0; ci0 < 512; ci0 += 16) {
            __syncthreads();   // protect previous iteration's LDS reads
            // ---- stage A: 4 elements ----
#pragma unroll
            for (int e = 0; e < 4; ++e) {
                const int idx = tid + e * 256;
                const int cia = idx >> 6;
                const int coa = idx & 63;
                Al[cia][coa] = Uf[(size_t)(ci0 + cia) * 512 + co0 + coa];
            }
            // ---- stage B: 2 elements (on-the-fly input transform) ----
#pragma unroll
            for (int e = 0; e < 2; ++e) {
                const int idx  = tid + e * 256;
                const int cib  = idx >> 5;
                const int tloc = idx & 31;
                const float* xc = xb + (size_t)(ci0 + cib) * NHW;
                double daa = 0.0, dab = 0.0, dba = 0.0, dbb = 0.0;
                if (bok[e]) {
                    const int r1i = ra[e], r2i = rb[e];
                    const int c1i = ca[e], c2i = cb[e];
                    if ((unsigned)r1i < (unsigned)NH) {
                        if ((unsigned)c1i < (unsigned)NW) daa = (double)xc[r1i * NW + c1i];
                        if ((unsigned)c2i < (unsigned)NW) dab = (double)xc[r1i * NW + c2i];
                    }
                    if ((unsigned)r2i < (unsigned)NH) {
                        if ((unsigned)c1i < (unsigned)NW) dba = (double)xc[r2i * NW + c1i];
                        if ((unsigned)c2i < (unsigned)NW) dbb = (double)xc[r2i * NW + c2i];
                    }
                }
                Bl[cib][tloc] = sx1 * (sn1 * daa + sn2 * dab)
                              + sx2 * (sn1 * dba + sn2 * dbb);
            }
            __syncthreads();

            // ---- FMA block ----
#pragma unroll
            for (int k = 0; k < 16; ++k) {
                double av[4], bv[2];
#pragma unroll
                for (int m = 0; m < 4; ++m) av[m] = Al[k][ty * 4 + m];
#pragma unroll
                for (int n = 0; n < 2; ++n) bv[n] = Bl[k][tx * 2 + n];
#pragma unroll
                for (int m = 0; m < 4; ++m)
#pragma unroll
                    for (int n = 0; n < 2; ++n) acc[m][n] += av[m] * bv[n];
            }
        }

        // ---- fold this freq into Y with A^T coefficients (0/+-1, exact) ----
        const double c00 = CA0[xi] * CA0[nu], c01 = CA0[xi] * CA1[nu];
        const double c10 = CA1[xi] * CA0[nu], c11 = CA1[xi] * CA1[nu];
#pragma unroll
        for (int m = 0; m < 4; ++m)
#pragma unroll
            for (int n = 0; n < 2; ++n) {
                const double a = acc[m][n];
                y[m][n][0][0] += c00 * a;
                y[m][n][0][1] += c01 * a;
                y[m][n][1][0] += c10 * a;
                y[m][n][1][1] += c11 * a;
            }
    }

    // ---- epilogue: bias + ReLU + f32 store ----
#pragma unroll
    for (int m = 0; m < 4; ++m) {
        const int co = co0 + ty * 4 + m;
        const double bi = (double)bias[co];
        float* orow = out + ((size_t)b * NC + co) * NHW;
#pragma unroll
        for (int n = 0; n < 2; ++n) {
            const int tg = t0 + tx * 2 + n;
            if (tg < NTILE) {
                const int tyt = tg / 25;
                const int txt = tg - tyt * 25;
                const int base = (tyt * 2) * NW + txt * 2;
#pragma unroll
                for (int i = 0; i < 2; ++i)
#pragma unroll
                    for (int j = 0; j < 2; ++j) {
                        const double d = y[m][n][i][j] + bi;
                        orow[base + i * NW + j] = (float)(d > 0.0 ? d : 0.0);
                    }
            }
        }
    }
}

// ---------------------------------------------------------------------------
// Kernel 2a: head partial (verified r15): 6-way output split; per-output
// c-order serial 0..511 -> f32 logits/locs. Grid (119, 6), block 256.
// ---------------------------------------------------------------------------
__global__ __launch_bounds__(256)
void head_part(const float* __restrict__ act,
               const float* __restrict__ cls_w, const float* __restrict__ cls_b,
               const float* __restrict__ reg_w, const float* __restrict__ reg_b,
               float* __restrict__ hl)
{
    const int p = blockIdx.x * 256 + threadIdx.x;
    if (p >= NPOS) return;
    const int g  = blockIdx.y;
    const int b  = p / NHW;
    const int hw = p - b * NHW;

    const float* av = act + (size_t)b * NC * NHW + hw;

    const float* wrow[9];
    double bia[9];
#pragma unroll
    for (int j = 0; j < 9; ++j) {
        const int o = g * 9 + j;
        if (o < 18) { wrow[j] = cls_w + (size_t)o * NC;        bia[j] = (double)cls_b[o]; }
        else        { wrow[j] = reg_w + (size_t)(o - 18) * NC; bia[j] = (double)reg_b[o - 18]; }
    }

    double acc[9];
#pragma unroll
    for (int j = 0; j < 9; ++j) acc[j] = 0.0;

    for (int c = 0; c < NC; ++c) {
        const double v = (double)av[(size_t)c * NHW];
#pragma unroll
        for (int j = 0; j < 9; ++j) acc[j] += v * (double)wrow[j][c];
    }

    float* hb = hl + (size_t)b * 54 * NHW + hw;
#pragma unroll
    for (int j = 0; j < 9; ++j)
        hb[(size_t)(g * 9 + j) * NHW] = (float)(acc[j] + bia[j]);
}

// ---------------------------------------------------------------------------
// Kernel 2b: decode (verified r15, byte-identical).
// ---------------------------------------------------------------------------
__global__ __launch_bounds__(256)
void decode_k(const float* __restrict__ hl,
              float* __restrict__ boxes, float* __restrict__ scores)
{
    const int p = blockIdx.x * 256 + threadIdx.x;
    if (p >= NPOS) return;
    const int b  = p / NHW;
    const int hw = p - b * NHW;

    const float* hb = hl + (size_t)b * 54 * NHW + hw;

    float lg[18];
#pragma unroll
    for (int o = 0; o < 18; ++o) lg[o] = hb[(size_t)o * NHW];
    float loc[36];
#pragma unroll
    for (int o = 0; o < 36; ++o) loc[o] = hb[(size_t)(18 + o) * NHW];

    double mx = -1e300;
#pragma unroll
    for (int o = 0; o < 18; ++o) mx = fmax(mx, (double)lg[o]);
    double sum = 0.0;
#pragma unroll
    for (int o = 0; o < 18; ++o) sum += exp((double)lg[o] - mx);
    const double inv = 1.0 / sum;

    const int hy = hw / NW;
    const int hx = hw - hy * NW;
    const float shy = (float)(hy * 16);
    const float shx = (float)(hx * 16);

    const double rats[3] = {0.5, 1.0, 2.0};
    const double scls[3] = {8.0, 16.0, 32.0};

#pragma unroll
    for (int a = 0; a < 9; ++a) {
        const int ir = a / 3, is = a - ir * 3;
        const double hh = 16.0 * scls[is] * sqrt(rats[ir]);
        const double wd = 16.0 * scls[is] * sqrt(1.0 / rats[ir]);
        const float ay1 = (float)(8.0 - hh * 0.5) + shy;
        const float ax1 = (float)(8.0 - wd * 0.5) + shx;
        const float ay2 = (float)(8.0 + hh * 0.5) + shy;
        const float ax2 = (float)(8.0 + wd * 0.5) + shx;
        const float ahf = ay2 - ay1;
        const float awf = ax2 - ax1;
        const float acy = ay1 + 0.5f * ahf;
        const float acx = ax1 + 0.5f * awf;

        const double ah = (double)ahf, aw = (double)awf;
        const double dy = (double)loc[4 * a + 0];
        const double dx = (double)loc[4 * a + 1];
        const double dh = (double)loc[4 * a + 2];
        const double dw = (double)loc[4 * a + 3];
        const double cy = dy * ah + (double)acy;
        const double cx = dx * aw + (double)acx;
        const double bh = exp(dh) * ah;
        const double bw = exp(dw) * aw;
        float y1 = (float)(cy - 0.5 * bh);
        float x1 = (float)(cx - 0.5 * bw);
        float y2 = (float)(cy + 0.5 * bh);
        float x2 = (float)(cx + 0.5 * bw);
        y1 = fminf(fmaxf(y1, 0.f), IMGH);
        y2 = fminf(fmaxf(y2, 0.f), IMGH);
        x1 = fminf(fmaxf(x1, 0.f), IMGW);
        x2 = fminf(fmaxf(x2, 0.f), IMGW);
        const bool keep = ((y2 - y1) >= 16.0f) && ((x2 - x1) >= 16.0f);

        float sc = (float)(exp((double)lg[2 * a + 1] - mx) * inv);
        if (!keep) sc = -INFINITY;

        const int n = hw * 9 + a;
        float4 bx; bx.x = y1; bx.y = x1; bx.z = y2; bx.w = x2;
        *reinterpret_cast<float4*>(&boxes[((size_t)b * NANCH + n) * 4]) = bx;
        scores[(size_t)b * NANCH + n] = sc;
    }
}

// ---------------------------------------------------------------------------
// Kernel 3: exact rank sort (verified r4, byte-identical).
// ---------------------------------------------------------------------------
__global__ __launch_bounds__(256)
void rank2(const float* __restrict__ scores, const float* __restrict__ boxes,
           float* __restrict__ sortedS, float* __restrict__ sortedB)
{
    const int b = blockIdx.y;
    const int i = blockIdx.x * 256 + threadIdx.x;
    if (i >= NANCH) return;
    const float si = scores[(size_t)b * NANCH + i];
    const float* sb = scores + (size_t)b * NANCH;
    int rank = 0;
    for (int j = 0; j < NANCH; ++j) {
        const float sj = sb[j];
        rank += (sj > si) || (sj == si && j < i);
    }
    if (rank < PRE_N) {
        sortedS[(size_t)b * PRE_N + rank] = si;
        const float4 bx = *reinterpret_cast<const float4*>(&boxes[((size_t)b * NANCH + i) * 4]);
        *reinterpret_cast<float4*>(&sortedB[((size_t)b * PRE_N + rank) * 4]) = bx;
    }
}

// ---------------------------------------------------------------------------
// Kernel 4: greedy NMS, kept-list (proven r7/r8; fastest tail config, r16).
// ---------------------------------------------------------------------------
__global__ __launch_bounds__(64)
void nms3(const float* __restrict__ sortedS, const float* __restrict__ sortedB,
          float* __restrict__ out)
{
    const int b    = blockIdx.x;
    const int lane = threadIdx.x;

    __shared__ float ky1[POST_N], kx1[POST_N], ky2[POST_N], kx2[POST_N];
    __shared__ float kar[POST_N], ksc[POST_N];
    __shared__ float cs[256];
    __shared__ float cb[256][4];

    const float* SS = sortedS + (size_t)b * PRE_N;
    const float* BB = sortedB + (size_t)b * PRE_N * 4;

    int nk = 0;
    bool done = false;
    for (int c0 = 0; c0 < PRE_N && !done; c0 += 256) {
        __syncthreads();
        for (int i = lane; i < 256; i += 64) {
            const int gi = c0 + i;
            if (gi < PRE_N) {
                cs[i] = SS[gi];
                const float4 bx = *reinterpret_cast<const float4*>(&BB[(size_t)gi * 4]);
                cb[i][0] = bx.x; cb[i][1] = bx.y; cb[i][2] = bx.z; cb[i][3] = bx.w;
            } else {
                cs[i] = -INFINITY;
                cb[i][0] = 0.f; cb[i][1] = 0.f; cb[i][2] = 0.f; cb[i][3] = 0.f;
            }
        }
        __syncthreads();

        for (int ic = 0; ic < 256; ++ic) {
            const float sc = cs[ic];
            if (sc == -INFINITY) { done = true; break; }
            const float y1 = cb[ic][0], x1 = cb[ic][1];
            const float y2 = cb[ic][2], x2 = cb[ic][3];
            const float areaC = fmaxf(y2 - y1, 0.f) * fmaxf(x2 - x1, 0.f);
            bool sup = false;
            for (int t = lane; t < nk; t += 64) {
                const float yy1 = fmaxf(y1, ky1[t]);
                const float xx1 = fmaxf(x1, kx1[t]);
                const float yy2 = fminf(y2, ky2[t]);
                const float xx2 = fminf(x2, kx2[t]);
                const float inter = fmaxf(yy2 - yy1, 0.f) * fmaxf(xx2 - xx1, 0.f);
                const float iou = inter / (areaC + kar[t] - inter + 1e-9f);
                if (iou > 0.7f) sup = true;
            }
            if (__ballot(sup) == 0ull) {
                if (lane == 0) {
                    ky1[nk] = y1; kx1[nk] = x1; ky2[nk] = y2; kx2[nk] = x2;
                    kar[nk] = areaC; ksc[nk] = sc;
                }
                __syncthreads();
                ++nk;
                if (nk == POST_N) { done = true; break; }
            }
        }
    }

    __syncthreads();
    for (int k2 = lane; k2 < POST_N; k2 += 64) {
        float o0 = 0.f, o1 = 0.f, o2 = 0.f, o3 = 0.f, o4 = 0.f;
        if (k2 < nk) {
            o0 = ky1[k2]; o1 = kx1[k2]; o2 = ky2[k2]; o3 = kx2[k2]; o4 = ksc[k2];
        }
        float* orow = out + ((size_t)b * POST_N + k2) * 5;
        orow[0] = o0; orow[1] = o1; orow[2] = o2; orow[3] = o3; orow[4] = o4;
    }
}

// ---------------------------------------------------------------------------
static const float* pick_input(void* const* d_in, const int* in_sizes, int n_in,
                               int want, int fallback)
{
    for (int i = 0; i < n_in; ++i)
        if (in_sizes[i] == want) return (const float*)d_in[i];
    return (const float*)d_in[fallback];
}

extern "C" void kernel_launch(void* const* d_in, const int* in_sizes, int n_in,
                              void* d_out, int out_size, void* d_ws, size_t ws_size,
                              hipStream_t stream)
{
    const float* x       = pick_input(d_in, in_sizes, n_in, 15564800, 0);
    const float* share_w = pick_input(d_in, in_sizes, n_in, 2359296, 1);
    const float* share_b = pick_input(d_in, in_sizes, n_in, 512, 2);
    const float* cls_w   = pick_input(d_in, in_sizes, n_in, 9216, 3);
    const float* cls_b   = pick_input(d_in, in_sizes, n_in, 18, 4);
    const float* reg_w   = pick_input(d_in, in_sizes, n_in, 18432, 5);
    const float* reg_b   = pick_input(d_in, in_sizes, n_in, 36, 6);
    float* out = (float*)d_out;

    // workspace layout (floats); total 27,443,008 = 109.8 MB (132 MB proven r7)
    float* W = (float*)d_ws;
    float*  act     = W;                    // 16*512*1900 = 15,564,800
    float*  boxes   = W + 15564800;         //  1,094,400
    float*  scores  = W + 16659200;         //    273,600
    float*  sortedB = W + 16932800;         //    384,000
    float*  sortedS = W + 17316800;         //     96,000
    float*  hl      = W + 17412800;         //  1,641,600
    double* U       = (double*)(W + 19054400); // 16*512*512 f64 = 8,388,608 floats

    wino_filter<<<dim3(1024), 256, 0, stream>>>(share_w, U);

    conv_wino<<<dim3(15, 8, NB), 256, 0, stream>>>(x, U, share_b, act);

    head_part<<<dim3(119, 6), 256, 0, stream>>>(act, cls_w, cls_b,
                                                reg_w, reg_b, hl);

    decode_k<<<dim3(119), 256, 0, stream>>>(hl, boxes, scores);

    rank2<<<dim3(67, 16), 256, 0, stream>>>(scores, boxes, sortedS, sortedB);

    nms3<<<dim3(16), 64, 0, stream>>>(sortedS, sortedB, out);
}